// Round 5
// baseline (84.195 us; speedup 1.0000x reference)
//
#include <hip/hip_runtime.h>

#define NBODY 8192
#define BLOCK 256
#define IPT 4                        // i-bodies per thread
#define ITILE (BLOCK * IPT)          // 1024 i-bodies per block
#define NITILES (NBODY / ITILE)      // 8
#define NGROUPS (NBODY / 64)         // 128 j-groups of 64 bodies
#define GPT (ITILE / 64)             // 16 j-groups per i-tile
#define SOFT2 1.0e-4f                // 0.01^2

// Pull value from lane (lane+1)&63 : full-wave rotate-by-1 (ds_bpermute).
__device__ __forceinline__ float rotf(int rotidx, float v) {
  return __int_as_float(
      __builtin_amdgcn_ds_bpermute(rotidx, __float_as_int(v)));
}

// Newton-3rd-law kernel. Grid (8, 128): block (x, g) pairs i-tile x (1024
// bodies, IPT=4) with j-group g (64 bodies).
//   g <  16x        : lower triangle -> covered by block (T(g), group(x)) sym.
//   16x <= g < 16x+16: same-tile     -> non-symmetric 12-op form (i-acc only).
//   g >= 16(x+1)    : symmetric 16-op form, one rsq per UNORDERED pair.
// Each wave keeps the 64 j-bodies (x,y,z,m) + traveling j-accumulators in
// registers and rotates them lane->lane-1 each step (7 ds_bpermute, amortized
// over 8 interactions/lane/step). After 64 steps everything is home; the 4
// waves' j-acc copies are merged in LDS and atomically added to out.
// Scheduling levers (occupancy 4/8 waves, IPT 1-4, DS amortization, burst
// hoist) were all ~null in R0-R4 -> this round cuts the op count instead:
// -33% full-rate VALU, -50% v_rsq.
__global__ __launch_bounds__(BLOCK) void force_kernel(
    const float* __restrict__ pos, const float* __restrict__ mass,
    float* __restrict__ out) {
  const int x = blockIdx.x;
  const int g = blockIdx.y;
  if (g < x * GPT) return;                 // symmetry: handled elsewhere
  const bool sym = (g >= (x + 1) * GPT);   // strictly higher tile

  __shared__ float jmerge[BLOCK / 64][64][3];

  const int t = threadIdx.x;
  const int lane = t & 63;
  const int wv = t >> 6;
  const int jbase = g * 64;
  const int ibase = x * ITILE;

  // i-bodies (4 per thread, strided by BLOCK)
  float xi[IPT], yi[IPT], zi[IPT], mi[IPT];
  float ax[IPT], ay[IPT], az[IPT];
#pragma unroll
  for (int p = 0; p < IPT; ++p) {
    const int i = ibase + p * BLOCK + t;
    xi[p] = pos[i * 3 + 0];
    yi[p] = pos[i * 3 + 1];
    zi[p] = pos[i * 3 + 2];
    mi[p] = mass[i];
    ax[p] = 0.f;
    ay[p] = 0.f;
    az[p] = 0.f;
  }

  // resident j-body + traveling accumulator (per lane; same group all waves)
  const int j = jbase + lane;
  float jx = pos[j * 3 + 0];
  float jy = pos[j * 3 + 1];
  float jz = pos[j * 3 + 2];
  float jm = mass[j];
  float jax = 0.f, jay = 0.f, jaz = 0.f;

  const int rotidx = ((lane + 1) & 63) * 4;  // byte index for ds_bpermute

  if (sym) {
#pragma unroll 2
    for (int s = 0; s < 64; ++s) {
#pragma unroll
      for (int p = 0; p < IPT; ++p) {
        float dx = jx - xi[p];
        float dy = jy - yi[p];
        float dz = jz - zi[p];
        float r2 = fmaf(dx, dx, fmaf(dy, dy, fmaf(dz, dz, SOFT2)));
        float inv = __builtin_amdgcn_rsqf(r2);   // ONE rsq per pair
        float inv3 = (inv * inv) * inv;
        float wi = jm * inv3;                    // force on i from j
        float wj = mi[p] * inv3;                 // force on j from i
        ax[p] = fmaf(wi, dx, ax[p]);
        ay[p] = fmaf(wi, dy, ay[p]);
        az[p] = fmaf(wi, dz, az[p]);
        jax = fmaf(-wj, dx, jax);                // a_j += wj * (p_i - p_j)
        jay = fmaf(-wj, dy, jay);
        jaz = fmaf(-wj, dz, jaz);
      }
      jx = rotf(rotidx, jx);
      jy = rotf(rotidx, jy);
      jz = rotf(rotidx, jz);
      jm = rotf(rotidx, jm);
      jax = rotf(rotidx, jax);
      jay = rotf(rotidx, jay);
      jaz = rotf(rotidx, jaz);
    }

    // Merge the 4 waves' j-accumulator copies and scatter (sym blocks only).
    jmerge[wv][lane][0] = jax;
    jmerge[wv][lane][1] = jay;
    jmerge[wv][lane][2] = jaz;
    __syncthreads();
    if (t < 64 * 3) {
      const int jl = t / 3, c = t % 3;
      float s = jmerge[0][jl][c] + jmerge[1][jl][c] + jmerge[2][jl][c] +
                jmerge[3][jl][c];
      atomicAdd(&out[(jbase + jl) * 3 + c], s);
    }
  } else {
    // Same-tile: one-directional 12-op form (pair covered twice by design;
    // self-pair j==i gives d=0 -> zero contribution, no NaN).
#pragma unroll 2
    for (int s = 0; s < 64; ++s) {
#pragma unroll
      for (int p = 0; p < IPT; ++p) {
        float dx = jx - xi[p];
        float dy = jy - yi[p];
        float dz = jz - zi[p];
        float r2 = fmaf(dx, dx, fmaf(dy, dy, fmaf(dz, dz, SOFT2)));
        float inv = __builtin_amdgcn_rsqf(r2);
        float w = jm * ((inv * inv) * inv);
        ax[p] = fmaf(w, dx, ax[p]);
        ay[p] = fmaf(w, dy, ay[p]);
        az[p] = fmaf(w, dz, az[p]);
      }
      jx = rotf(rotidx, jx);
      jy = rotf(rotidx, jy);
      jz = rotf(rotidx, jz);
      jm = rotf(rotidx, jm);
    }
  }

  // i-accumulator scatter (R0-proven atomic epilogue; contention ~100/addr).
#pragma unroll
  for (int p = 0; p < IPT; ++p) {
    const int i = ibase + p * BLOCK + t;
    atomicAdd(&out[i * 3 + 0], ax[p]);
    atomicAdd(&out[i * 3 + 1], ay[p]);
    atomicAdd(&out[i * 3 + 2], az[p]);
  }
}

extern "C" void kernel_launch(void* const* d_in, const int* in_sizes, int n_in,
                              void* d_out, int out_size, void* d_ws,
                              size_t ws_size, hipStream_t stream) {
  const float* pos = (const float*)d_in[0];
  const float* mass = (const float*)d_in[1];
  float* out = (float*)d_out;

  // d_out is re-poisoned before each launch; atomics need zeros.
  hipMemsetAsync(d_out, 0, (size_t)out_size * sizeof(float), stream);

  force_kernel<<<dim3(NITILES, NGROUPS), BLOCK, 0, stream>>>(pos, mass, out);
}